// Round 5
// baseline (1099.081 us; speedup 1.0000x reference)
//
#include <hip/hip_runtime.h>
#include <math.h>

#define B_   128
#define L_   32
#define T_   31
#define V_   10000
#define IC_  2048
#define WD_  512
#define H_   512
#define D_   2560
#define G3_  1536   // 3*H
#define NPAD_ 10112 // V padded to 79*128

typedef short short8 __attribute__((ext_vector_type(8)));
typedef float f32x4  __attribute__((ext_vector_type(4)));

__device__ __forceinline__ unsigned short f2bf(float f) {
    unsigned int u = __builtin_bit_cast(unsigned int, f);
    unsigned int r = (u + 0x7FFFu + ((u >> 16) & 1u)) >> 16;
    return (unsigned short)r;
}
__device__ __forceinline__ float bf2f(unsigned short h) {
    unsigned int u = ((unsigned int)h) << 16;
    return __builtin_bit_cast(float, u);
}
__device__ __forceinline__ f32x4 mfma16(short8 a, short8 b, f32x4 c) {
    return __builtin_amdgcn_mfma_f32_16x16x32_bf16(a, b, c, 0, 0, 0);
}

// ---- workspace layout (byte offsets) ----
#define WS_ORDER  0          // int[128]
#define WS_LEN    512        // int[128]
#define WS_TOK    1024       // int[3968] -> ends 16896
#define WS_BAR    16896      // int barrier counter (zeroed by k_prep)
#define WS_GIIMG  16960      // float[128*1536]          -> ends 803392
#define WS_WHH    803392     // bf16 [16][96][512] perm  -> ends 2376256
#define WS_GIFULL 2376256    // bf16 [3968*1536]         -> ends 14565952
#define WS_OUTS   14565952   // bf16 [32*128*512]        -> ends 18760256
#define WS_FCW    18760256   // bf16 [10112*512]         -> ends 29114944

// ---------------------------------------------------------------------------
__global__ void k_prep(const int* __restrict__ captions,
                       const int* __restrict__ cap_lens,
                       int* __restrict__ order,
                       int* __restrict__ len_i,
                       int* __restrict__ tok,
                       int* __restrict__ bar,
                       float* __restrict__ out_tail) {
    __shared__ int s_len[B_];
    __shared__ int s_ord[B_];
    const int tid = threadIdx.x;
    if (tid == 0) *bar = 0;
    if (tid < B_) s_len[tid] = cap_lens[tid];
    __syncthreads();
    if (tid < B_) {
        const int myl = s_len[tid];
        int rank = 0;
        for (int k = 0; k < B_; ++k) {
            const int lk = s_len[k];
            if (lk > myl || (lk == myl && k < tid)) rank++;
        }
        s_ord[rank] = tid;
    }
    __syncthreads();
    if (tid < B_) {
        const int o = s_ord[tid];
        order[tid] = o;
        const int ln = s_len[o] - 1;
        len_i[tid] = ln;
        out_tail[B_ * L_ + tid]      = (float)ln;
        out_tail[B_ * L_ + B_ + tid] = (float)o;
    }
    __syncthreads();
    for (int i = tid; i < B_ * L_; i += blockDim.x) {
        const int b = i / L_, l = i % L_;
        const int c = captions[s_ord[b] * L_ + l];
        out_tail[i] = (float)c;
        if (l < T_) tok[l * B_ + b] = c;
    }
}

// fc_w (10000x512 f32) -> bf16 padded to 10112 rows (zero tail)
__global__ void k_cvt_fcw(const float* __restrict__ src, unsigned short* __restrict__ dst) {
    const int idx = blockIdx.x * 256 + threadIdx.x;
    const int row = idx >> 6;
    const int ch  = idx & 63;
    union { unsigned short u[8]; uint4 v; } r;
    if (row < V_) {
        const float* p = src + (size_t)row * 512 + ch * 8;
        const float4 x = *(const float4*)p;
        const float4 y = *(const float4*)(p + 4);
        r.u[0]=f2bf(x.x); r.u[1]=f2bf(x.y); r.u[2]=f2bf(x.z); r.u[3]=f2bf(x.w);
        r.u[4]=f2bf(y.x); r.u[5]=f2bf(y.y); r.u[6]=f2bf(y.z); r.u[7]=f2bf(y.w);
    } else {
        r.v = make_uint4(0, 0, 0, 0);
    }
    *(uint4*)&dst[(size_t)row * 512 + ch * 8] = r.v;
}

// W_hh (1536x512 f32) -> bf16, permuted into 16 slices of 96x512:
// slice g, local row j (= gate*32 + c) <- source row gate*512 + g*32 + c
__global__ void k_cvt_whh(const float* __restrict__ whh, unsigned short* __restrict__ dst) {
    const int idx = blockIdx.x * 256 + threadIdx.x;
    const size_t o = (size_t)idx * 8;
    const int g = (int)(o / (96 * 512));
    const int rem = (int)(o % (96 * 512));
    const int j = rem >> 9;
    const int k = rem & 511;
    const int srow = (j >> 5) * 512 + g * 32 + (j & 31);
    const float* p = whh + (size_t)srow * 512 + k;
    const float4 x = *(const float4*)p;
    const float4 y = *(const float4*)(p + 4);
    union { unsigned short u[8]; uint4 v; } r;
    r.u[0]=f2bf(x.x); r.u[1]=f2bf(x.y); r.u[2]=f2bf(x.z); r.u[3]=f2bf(x.w);
    r.u[4]=f2bf(y.x); r.u[5]=f2bf(y.y); r.u[6]=f2bf(y.z); r.u[7]=f2bf(y.w);
    *(uint4*)&dst[o] = r.v;
}

// ---------------------------------------------------------------------------
template<bool F32>
__device__ __forceinline__ uint4 load_cvt(const void* src, size_t off) {
    if constexpr (!F32) {
        return *(const uint4*)((const unsigned short*)src + off);
    } else {
        const float* p = (const float*)src + off;
        const float4 x = *(const float4*)p;
        const float4 y = *(const float4*)(p + 4);
        union { unsigned short u[8]; uint4 v; } r;
        r.u[0]=f2bf(x.x); r.u[1]=f2bf(x.y); r.u[2]=f2bf(x.z); r.u[3]=f2bf(x.w);
        r.u[4]=f2bf(y.x); r.u[5]=f2bf(y.y); r.u[6]=f2bf(y.z); r.u[7]=f2bf(y.w);
        return r.v;
    }
}

// epilogues
struct EpiBiasF32 {               // gi_img
    float* C; int ldc; const float* bias;
    __device__ void operator()(int m, int n, float v) const {
        C[(size_t)m * ldc + n] = v + bias[n];
    }
};
struct EpiBiasBF16 {              // h0 -> outs rows [0,128)
    unsigned short* C; int ldc; const float* bias;
    __device__ void operator()(int m, int n, float v) const {
        C[(size_t)m * ldc + n] = f2bf(v + bias[n]);
    }
};
struct EpiAdd2D {                 // gi_full = giw + gi_img[b] (+ b_hh for r,z)
    unsigned short* C; int ldc; const float* add; int addld; const float* bhh;
    __device__ void operator()(int m, int n, float v) const {
        const float extra = (n < 1024) ? bhh[n] : 0.f;
        C[(size_t)m * ldc + n] = f2bf(v + add[(size_t)(m & 127) * addld + n] + extra);
    }
};
struct EpiPreds {                 // masked transpose store
    float* out; const float* fcb; const int* len;
    __device__ void operator()(int m, int n, float v) const {
        if (n >= V_) return;
        const int t = m >> 7, b = m & 127;
        const float r = (t < len[b]) ? (v + fcb[n]) : 0.f;
        out[(size_t)b * T_ * V_ + (size_t)t * V_ + n] = r;
    }
};

// ---------------------------------------------------------------------------
// NT GEMM, 128x128 tile, BK=32, 256 thr / 4 waves, bf16 MFMA 16x16x32.
// ---------------------------------------------------------------------------
template<bool AF32, bool BF32, class Epi>
__global__ __launch_bounds__(256) void gemm128(
    const void* __restrict__ A, int lda, const int* __restrict__ gidx,
    const void* __restrict__ Bm, int ldb, int K, Epi epi)
{
    __shared__ unsigned short As[128 * 32];
    __shared__ unsigned short Bs[128 * 32];
    const int tid = threadIdx.x;
    const int m0 = blockIdx.y * 128, n0 = blockIdx.x * 128;
    const int w = tid >> 6, lane = tid & 63, quad = lane >> 4, lr = lane & 15;
    const int srow = tid >> 2, ch = tid & 3;
    const int wm = (w & 1) * 64, wn = (w >> 1) * 64;

    const int ar0 = gidx ? gidx[m0 + srow]      : (m0 + srow);
    const int ar1 = gidx ? gidx[m0 + srow + 64] : (m0 + srow + 64);
    const int br0 = n0 + srow, br1 = n0 + srow + 64;

    f32x4 acc[4][4];
    const f32x4 z4 = {0.f, 0.f, 0.f, 0.f};
#pragma unroll
    for (int i = 0; i < 4; ++i)
#pragma unroll
        for (int j = 0; j < 4; ++j) acc[i][j] = z4;

    for (int k0 = 0; k0 < K; k0 += 32) {
        const uint4 a0 = load_cvt<AF32>(A, (size_t)ar0 * lda + k0 + ch * 8);
        const uint4 a1 = load_cvt<AF32>(A, (size_t)ar1 * lda + k0 + ch * 8);
        const uint4 b0 = load_cvt<BF32>(Bm, (size_t)br0 * ldb + k0 + ch * 8);
        const uint4 b1 = load_cvt<BF32>(Bm, (size_t)br1 * ldb + k0 + ch * 8);
        __syncthreads();
        *(uint4*)&As[(srow)      * 32 + ch * 8] = a0;
        *(uint4*)&As[(srow + 64) * 32 + ch * 8] = a1;
        *(uint4*)&Bs[(srow)      * 32 + ch * 8] = b0;
        *(uint4*)&Bs[(srow + 64) * 32 + ch * 8] = b1;
        __syncthreads();
        short8 af[4], bfr[4];
#pragma unroll
        for (int i = 0; i < 4; ++i) af[i]  = *(const short8*)&As[(wm + i * 16 + lr) * 32 + quad * 8];
#pragma unroll
        for (int j = 0; j < 4; ++j) bfr[j] = *(const short8*)&Bs[(wn + j * 16 + lr) * 32 + quad * 8];
#pragma unroll
        for (int i = 0; i < 4; ++i)
#pragma unroll
            for (int j = 0; j < 4; ++j) acc[i][j] = mfma16(af[i], bfr[j], acc[i][j]);
    }

#pragma unroll
    for (int i = 0; i < 4; ++i)
#pragma unroll
        for (int r = 0; r < 4; ++r) {
            const int m = m0 + wm + i * 16 + quad * 4 + r;
#pragma unroll
            for (int j = 0; j < 4; ++j) {
                const int n = n0 + wn + j * 16 + lr;
                epi(m, n, acc[i][j][r]);
            }
        }
}

// ---------------------------------------------------------------------------
// Persistent recurrence: 16 blocks (g 0..15) x 512 threads (8 waves:
// waves 0-3 -> batch rows 0-63, waves 4-7 -> rows 64-127).
// Cross-block h exchange via agent-scope RELAXED atomics (write-through /
// L2-bypass) -- NO cache-sweeping fences. Release = per-wave
// s_waitcnt vmcnt(0) before the relaxed barrier increment.
// ---------------------------------------------------------------------------
#define BS_STR 520
#define AS_STR 136
__global__ __launch_bounds__(512, 1) void k_recur(
    const unsigned short* __restrict__ whh_bf,   // (16,96,512)
    const unsigned short* __restrict__ gi_full,  // (31*128,1536)
    const float* __restrict__ b_hh,              // (1536)
    unsigned short* __restrict__ outs,           // (32,128,512)
    int* __restrict__ bar)
{
    __shared__ unsigned short Bs[96 * BS_STR];   //  99,840 B
    __shared__ unsigned short As[128 * AS_STR];  //  34,816 B
    const int tid = threadIdx.x;
    const int g = blockIdx.x;            // 0..15
    const int w = tid >> 6;              // 0..7
    const int ih = w >> 2;               // 0..1
    const int wloc = w & 3;              // 0..3
    const int lane = tid & 63, quad = lane >> 4, lr = lane & 15;

    // one-time: W slice (96x512) -> LDS, resident for all steps.
    // 512 cols = 64 groups of 8 bf16 per row (R4 bug: used 32 -> half of Bs
    // uninitialized -> NaN).
    {
        const unsigned short* src = whh_bf + (size_t)g * 96 * 512;
        for (int i = tid; i < 96 * 64; i += 512) {
            const int row = i >> 6, c16 = i & 63;
            *(uint4*)&Bs[row * BS_STR + c16 * 8] = *(const uint4*)&src[row * 512 + c16 * 8];
        }
    }
    const float bhn0 = b_hh[1024 + g * 32 + lr];
    const float bhn1 = b_hh[1024 + g * 32 + 16 + lr];
    const int hold_kc = (g >> 2) * 128;          // h chunk containing our gh cols
    __syncthreads();

    for (int step = 0; step < T_; ++step) {
        // prefetch gi operands for this step (plain cached loads, used in gates)
        unsigned short gi_raw[2][4][3];
        const size_t gbase = (size_t)step * 128 * G3_;
#pragma unroll
        for (int jj = 0; jj < 2; ++jj) {
            const int cg = g * 32 + jj * 16 + lr;
#pragma unroll
            for (int r = 0; r < 4; ++r) {
                const int b = ih * 64 + wloc * 16 + quad * 4 + r;
                const unsigned short* p = gi_full + gbase + (size_t)b * G3_ + cg;
                gi_raw[jj][r][0] = p[0];
                gi_raw[jj][r][1] = p[512];
                gi_raw[jj][r][2] = p[1024];
            }
        }

        f32x4 acc[6];
#pragma unroll
        for (int j = 0; j < 6; ++j) acc[j] = (f32x4){0.f, 0.f, 0.f, 0.f};
        unsigned short hold_raw[2][4];

        const unsigned short* hsrc = outs + (size_t)step * (128 * 512);
        for (int kc = 0; kc < 512; kc += 128) {
            __syncthreads();
            // stage h[*, kc..kc+128) via L2-bypassing 8B atomic loads
            for (int i = tid; i < 128 * 32; i += 512) {
                const int row = i >> 5, c8 = i & 31;
                unsigned long long v = __hip_atomic_load(
                    (unsigned long long*)&hsrc[(size_t)row * 512 + kc + c8 * 4],
                    __ATOMIC_RELAXED, __HIP_MEMORY_SCOPE_AGENT);
                *(unsigned long long*)&As[row * AS_STR + c8 * 4] = v;
            }
            __syncthreads();
#pragma unroll
            for (int kl = 0; kl < 128; kl += 32) {
                const short8 af = *(const short8*)&As[(ih * 64 + wloc * 16 + lr) * AS_STR + kl + quad * 8];
#pragma unroll
                for (int j = 0; j < 6; ++j) {
                    const short8 bf = *(const short8*)&Bs[(j * 16 + lr) * BS_STR + kc + kl + quad * 8];
                    acc[j] = mfma16(af, bf, acc[j]);
                }
            }
            if (kc == hold_kc) {   // capture h_old for the gates from LDS
#pragma unroll
                for (int jj = 0; jj < 2; ++jj) {
                    const int off = (g & 3) * 32 + jj * 16 + lr;
#pragma unroll
                    for (int r = 0; r < 4; ++r) {
                        const int b = ih * 64 + wloc * 16 + quad * 4 + r;
                        hold_raw[jj][r] = As[b * AS_STR + off];
                    }
                }
            }
        }

        // gates in registers (C-layout: col=lr, row=quad*4+r)
        unsigned short* hdst = outs + (size_t)(step + 1) * (128 * 512);
#pragma unroll
        for (int jj = 0; jj < 2; ++jj) {
            const int cg = g * 32 + jj * 16 + lr;
            const float bhn = jj ? bhn1 : bhn0;
#pragma unroll
            for (int r = 0; r < 4; ++r) {
                const int b = ih * 64 + wloc * 16 + quad * 4 + r;
                const float ir  = bf2f(gi_raw[jj][r][0]);
                const float iz  = bf2f(gi_raw[jj][r][1]);
                const float in_ = bf2f(gi_raw[jj][r][2]);
                const float hr = acc[jj][r];
                const float hz = acc[2 + jj][r];
                const float hn = acc[4 + jj][r] + bhn;
                const float rg = 1.f / (1.f + __expf(-(ir + hr)));
                const float zg = 1.f / (1.f + __expf(-(iz + hz)));
                const float nn = tanhf(in_ + rg * hn);
                const float hold = bf2f(hold_raw[jj][r]);
                const float hnew = (1.f - zg) * nn + zg * hold;
                // pack bf16 pair across lane pairs -> one 32-bit write-through store
                const unsigned int hv = (unsigned int)f2bf(hnew);
                const unsigned int pv = (unsigned int)__shfl_xor((int)hv, 1);
                if ((lr & 1) == 0) {
                    const unsigned int word = hv | (pv << 16);
                    __hip_atomic_store(
                        (unsigned int*)&hdst[(size_t)b * 512 + cg], word,
                        __ATOMIC_RELAXED, __HIP_MEMORY_SCOPE_AGENT);
                }
            }
        }

        // hand-rolled release: drain this wave's write-through stores, then signal
        asm volatile("s_waitcnt vmcnt(0)" ::: "memory");
        __syncthreads();
        if (tid == 0) {
            __hip_atomic_fetch_add(bar, 1, __ATOMIC_RELAXED, __HIP_MEMORY_SCOPE_AGENT);
            if (step < T_ - 1) {
                const int target = 16 * (step + 1);
                while (__hip_atomic_load(bar, __ATOMIC_RELAXED, __HIP_MEMORY_SCOPE_AGENT) < target)
                    __builtin_amdgcn_s_sleep(1);
            }
        }
        __syncthreads();
        asm volatile("" ::: "memory");
    }
}

// ---------------------------------------------------------------------------
extern "C" void kernel_launch(void* const* d_in, const int* in_sizes, int n_in,
                              void* d_out, int out_size, void* d_ws, size_t ws_size,
                              hipStream_t stream) {
    const float* image_code = (const float*)d_in[0];
    const int*   captions   = (const int*)d_in[1];
    const int*   cap_lens   = (const int*)d_in[2];
    const float* embed_w    = (const float*)d_in[3];
    const float* W_ih       = (const float*)d_in[4];
    const float* W_hh       = (const float*)d_in[5];
    const float* b_ih       = (const float*)d_in[6];
    const float* b_hh       = (const float*)d_in[7];
    const float* fc_w       = (const float*)d_in[8];
    const float* fc_b       = (const float*)d_in[9];
    const float* init_w     = (const float*)d_in[10];
    const float* init_b     = (const float*)d_in[11];

    float* out = (float*)d_out;
    char* ws = (char*)d_ws;
    int*            order   = (int*)(ws + WS_ORDER);
    int*            len_i   = (int*)(ws + WS_LEN);
    int*            tok     = (int*)(ws + WS_TOK);
    int*            bar     = (int*)(ws + WS_BAR);
    float*          gi_img  = (float*)(ws + WS_GIIMG);
    unsigned short* whh_bf  = (unsigned short*)(ws + WS_WHH);
    unsigned short* gi_full = (unsigned short*)(ws + WS_GIFULL);
    unsigned short* outs_bf = (unsigned short*)(ws + WS_OUTS);
    unsigned short* fcw_bf  = (unsigned short*)(ws + WS_FCW);

    // 1) sort + token table + barrier reset + int-ish outputs
    hipLaunchKernelGGL(k_prep, dim3(1), dim3(128), 0, stream,
                       captions, cap_lens, order, len_i, tok, bar,
                       out + (size_t)B_ * T_ * V_);

    // 2) weight conversions
    hipLaunchKernelGGL(k_cvt_fcw, dim3((NPAD_ * 64) / 256), dim3(256), 0, stream,
                       fc_w, fcw_bf);
    hipLaunchKernelGGL(k_cvt_whh, dim3((G3_ * H_ / 8) / 256), dim3(256), 0, stream,
                       W_hh, whh_bf);

    // 3) gi_img = ic_s @ W_ih[:, :2048]^T + b_ih
    hipLaunchKernelGGL((gemm128<true, true, EpiBiasF32>), dim3(12, 1), dim3(256), 0, stream,
                       image_code, IC_, order, W_ih, D_, IC_,
                       EpiBiasF32{gi_img, G3_, b_ih});

    // 4) h0 = ic_s @ init_w^T + init_b -> outs rows [0,128)
    hipLaunchKernelGGL((gemm128<true, true, EpiBiasBF16>), dim3(4, 1), dim3(256), 0, stream,
                       image_code, IC_, order, init_w, IC_, IC_,
                       EpiBiasBF16{outs_bf, H_, init_b});

    // 5) gi_full = emb @ W_ih[:, 2048:]^T + gi_img[b] + b_hh(r,z)
    hipLaunchKernelGGL((gemm128<true, true, EpiAdd2D>), dim3(12, 31), dim3(256), 0, stream,
                       embed_w, WD_, tok, W_ih + IC_, D_, WD_,
                       EpiAdd2D{gi_full, G3_, gi_img, G3_, b_hh});

    // 6) persistent recurrence (31 steps, 1 launch, fence-free barrier)
    hipLaunchKernelGGL(k_recur, dim3(16), dim3(512), 0, stream,
                       whh_bf, gi_full, b_hh, outs_bf, bar);

    // 7) preds = outs @ fc_w^T + fc_b, masked, transposed store
    hipLaunchKernelGGL((gemm128<false, false, EpiPreds>), dim3(NPAD_ / 128, 31), dim3(256), 0, stream,
                       outs_bf + (size_t)B_ * H_, H_, (const int*)nullptr,
                       fcw_bf, H_, H_,
                       EpiPreds{out, fc_b, len_i});
}

// Round 6
// 953.549 us; speedup vs baseline: 1.1526x; 1.1526x over previous
//
#include <hip/hip_runtime.h>
#include <math.h>

#define B_   128
#define L_   32
#define T_   31
#define V_   10000
#define IC_  2048
#define WD_  512
#define H_   512
#define D_   2560
#define G3_  1536   // 3*H
#define NPAD_ 10112 // V padded to 79*128
#define NCONS_ (79 * 31)          // consumer blocks
#define NPROD_ 64                 // producer blocks

typedef short short8 __attribute__((ext_vector_type(8)));
typedef float f32x4  __attribute__((ext_vector_type(4)));
typedef unsigned short ushort_t;
typedef unsigned long long ull_t;

__device__ __forceinline__ unsigned short f2bf(float f) {
    unsigned int u = __builtin_bit_cast(unsigned int, f);
    unsigned int r = (u + 0x7FFFu + ((u >> 16) & 1u)) >> 16;
    return (unsigned short)r;
}
__device__ __forceinline__ float bf2f(unsigned short h) {
    unsigned int u = ((unsigned int)h) << 16;
    return __builtin_bit_cast(float, u);
}
__device__ __forceinline__ f32x4 mfma16(short8 a, short8 b, f32x4 c) {
    return __builtin_amdgcn_mfma_f32_16x16x32_bf16(a, b, c, 0, 0, 0);
}
__device__ __forceinline__ ull_t ald8(const ushort_t* p) {
    return __hip_atomic_load((const ull_t*)p, __ATOMIC_RELAXED, __HIP_MEMORY_SCOPE_AGENT);
}

// ---- workspace layout (byte offsets) ----
#define WS_ORDER  0          // int[128]
#define WS_LEN    512        // int[128]
#define WS_TOK    1024       // int[3968] -> ends 16896
#define WS_BAR    16896      // int barrier counter (zeroed by k_prep)
#define WS_GIIMG  16960      // float[128*1536]          -> ends 803392
#define WS_WHH    803392     // bf16 [32][48][512] perm  -> ends 2376256
#define WS_GIFULL 2376256    // bf16 [3968*1536]         -> ends 14565952
#define WS_OUTS   14565952   // bf16 [32*128*512]        -> ends 18760256
#define WS_FCW    18760256   // bf16 [10112*512]         -> ends 29114944

// ---------------------------------------------------------------------------
__global__ void k_prep(const int* __restrict__ captions,
                       const int* __restrict__ cap_lens,
                       int* __restrict__ order,
                       int* __restrict__ len_i,
                       int* __restrict__ tok,
                       int* __restrict__ bar,
                       float* __restrict__ out_tail) {
    __shared__ int s_len[B_];
    __shared__ int s_ord[B_];
    const int tid = threadIdx.x;
    if (tid == 0) *bar = 0;
    if (tid < B_) s_len[tid] = cap_lens[tid];
    __syncthreads();
    if (tid < B_) {
        const int myl = s_len[tid];
        int rank = 0;
        for (int k = 0; k < B_; ++k) {
            const int lk = s_len[k];
            if (lk > myl || (lk == myl && k < tid)) rank++;
        }
        s_ord[rank] = tid;
    }
    __syncthreads();
    if (tid < B_) {
        const int o = s_ord[tid];
        order[tid] = o;
        const int ln = s_len[o] - 1;
        len_i[tid] = ln;
        out_tail[B_ * L_ + tid]      = (float)ln;
        out_tail[B_ * L_ + B_ + tid] = (float)o;
    }
    __syncthreads();
    for (int i = tid; i < B_ * L_; i += blockDim.x) {
        const int b = i / L_, l = i % L_;
        const int c = captions[s_ord[b] * L_ + l];
        out_tail[i] = (float)c;
        if (l < T_) tok[l * B_ + b] = c;
    }
}

// fc_w (10000x512 f32) -> bf16 padded to 10112 rows (zero tail)
__global__ void k_cvt_fcw(const float* __restrict__ src, ushort_t* __restrict__ dst) {
    const int idx = blockIdx.x * 256 + threadIdx.x;
    const int row = idx >> 6;
    const int ch  = idx & 63;
    union { unsigned short u[8]; uint4 v; } r;
    if (row < V_) {
        const float* p = src + (size_t)row * 512 + ch * 8;
        const float4 x = *(const float4*)p;
        const float4 y = *(const float4*)(p + 4);
        r.u[0]=f2bf(x.x); r.u[1]=f2bf(x.y); r.u[2]=f2bf(x.z); r.u[3]=f2bf(x.w);
        r.u[4]=f2bf(y.x); r.u[5]=f2bf(y.y); r.u[6]=f2bf(y.z); r.u[7]=f2bf(y.w);
    } else {
        r.v = make_uint4(0, 0, 0, 0);
    }
    *(uint4*)&dst[(size_t)row * 512 + ch * 8] = r.v;
}

// W_hh (1536x512 f32) -> bf16, permuted into 32 slices of 48x512:
// slice g, local row j (= gate*16 + c) <- source row gate*512 + g*16 + c
__global__ void k_cvt_whh(const float* __restrict__ whh, ushort_t* __restrict__ dst) {
    const int idx = blockIdx.x * 256 + threadIdx.x;
    const size_t o = (size_t)idx * 8;
    const int g = (int)(o / (48 * 512));
    const int rem = (int)(o % (48 * 512));
    const int j = rem >> 9;
    const int k = rem & 511;
    const int srow = (j >> 4) * 512 + g * 16 + (j & 15);
    const float* p = whh + (size_t)srow * 512 + k;
    const float4 x = *(const float4*)p;
    const float4 y = *(const float4*)(p + 4);
    union { unsigned short u[8]; uint4 v; } r;
    r.u[0]=f2bf(x.x); r.u[1]=f2bf(x.y); r.u[2]=f2bf(x.z); r.u[3]=f2bf(x.w);
    r.u[4]=f2bf(y.x); r.u[5]=f2bf(y.y); r.u[6]=f2bf(y.z); r.u[7]=f2bf(y.w);
    *(uint4*)&dst[o] = r.v;
}

// ---------------------------------------------------------------------------
template<bool F32>
__device__ __forceinline__ uint4 load_cvt(const void* src, size_t off) {
    if constexpr (!F32) {
        return *(const uint4*)((const unsigned short*)src + off);
    } else {
        const float* p = (const float*)src + off;
        const float4 x = *(const float4*)p;
        const float4 y = *(const float4*)(p + 4);
        union { unsigned short u[8]; uint4 v; } r;
        r.u[0]=f2bf(x.x); r.u[1]=f2bf(x.y); r.u[2]=f2bf(x.z); r.u[3]=f2bf(x.w);
        r.u[4]=f2bf(y.x); r.u[5]=f2bf(y.y); r.u[6]=f2bf(y.z); r.u[7]=f2bf(y.w);
        return r.v;
    }
}

// epilogues for the prefix GEMMs
struct EpiBiasF32 {               // gi_img
    float* C; int ldc; const float* bias;
    __device__ void operator()(int m, int n, float v) const {
        C[(size_t)m * ldc + n] = v + bias[n];
    }
};
struct EpiBiasBF16 {              // h0 -> outs rows [0,128)
    ushort_t* C; int ldc; const float* bias;
    __device__ void operator()(int m, int n, float v) const {
        C[(size_t)m * ldc + n] = f2bf(v + bias[n]);
    }
};
struct EpiAdd2D {                 // gi_full = giw + gi_img[b] (+ b_hh for r,z)
    ushort_t* C; int ldc; const float* add; int addld; const float* bhh;
    __device__ void operator()(int m, int n, float v) const {
        const float extra = (n < 1024) ? bhh[n] : 0.f;
        C[(size_t)m * ldc + n] = f2bf(v + add[(size_t)(m & 127) * addld + n] + extra);
    }
};

// ---------------------------------------------------------------------------
// NT GEMM, 128x128 tile, BK=32, 256 thr / 4 waves, bf16 MFMA 16x16x32.
// ---------------------------------------------------------------------------
template<bool AF32, bool BF32, class Epi>
__global__ __launch_bounds__(256) void gemm128(
    const void* __restrict__ A, int lda, const int* __restrict__ gidx,
    const void* __restrict__ Bm, int ldb, int K, Epi epi)
{
    __shared__ ushort_t As[128 * 32];
    __shared__ ushort_t Bs[128 * 32];
    const int tid = threadIdx.x;
    const int m0 = blockIdx.y * 128, n0 = blockIdx.x * 128;
    const int w = tid >> 6, lane = tid & 63, quad = lane >> 4, lr = lane & 15;
    const int srow = tid >> 2, ch = tid & 3;
    const int wm = (w & 1) * 64, wn = (w >> 1) * 64;

    const int ar0 = gidx ? gidx[m0 + srow]      : (m0 + srow);
    const int ar1 = gidx ? gidx[m0 + srow + 64] : (m0 + srow + 64);
    const int br0 = n0 + srow, br1 = n0 + srow + 64;

    f32x4 acc[4][4];
    const f32x4 z4 = {0.f, 0.f, 0.f, 0.f};
#pragma unroll
    for (int i = 0; i < 4; ++i)
#pragma unroll
        for (int j = 0; j < 4; ++j) acc[i][j] = z4;

    for (int k0 = 0; k0 < K; k0 += 32) {
        const uint4 a0 = load_cvt<AF32>(A, (size_t)ar0 * lda + k0 + ch * 8);
        const uint4 a1 = load_cvt<AF32>(A, (size_t)ar1 * lda + k0 + ch * 8);
        const uint4 b0 = load_cvt<BF32>(Bm, (size_t)br0 * ldb + k0 + ch * 8);
        const uint4 b1 = load_cvt<BF32>(Bm, (size_t)br1 * ldb + k0 + ch * 8);
        __syncthreads();
        *(uint4*)&As[(srow)      * 32 + ch * 8] = a0;
        *(uint4*)&As[(srow + 64) * 32 + ch * 8] = a1;
        *(uint4*)&Bs[(srow)      * 32 + ch * 8] = b0;
        *(uint4*)&Bs[(srow + 64) * 32 + ch * 8] = b1;
        __syncthreads();
        short8 af[4], bfr[4];
#pragma unroll
        for (int i = 0; i < 4; ++i) af[i]  = *(const short8*)&As[(wm + i * 16 + lr) * 32 + quad * 8];
#pragma unroll
        for (int j = 0; j < 4; ++j) bfr[j] = *(const short8*)&Bs[(wn + j * 16 + lr) * 32 + quad * 8];
#pragma unroll
        for (int i = 0; i < 4; ++i)
#pragma unroll
            for (int j = 0; j < 4; ++j) acc[i][j] = mfma16(af[i], bfr[j], acc[i][j]);
    }

#pragma unroll
    for (int i = 0; i < 4; ++i)
#pragma unroll
        for (int r = 0; r < 4; ++r) {
            const int m = m0 + wm + i * 16 + quad * 4 + r;
#pragma unroll
            for (int j = 0; j < 4; ++j) {
                const int n = n0 + wn + j * 16 + lr;
                epi(m, n, acc[i][j][r]);
            }
        }
}

// ---------------------------------------------------------------------------
// FUSED recurrence + output projection.
// Blocks [0,64): producers. g = bid&31 (16 gh cols x 3 gates), ih = bid>>5
//   (batch half). W slice 48x512 LDS-resident; per step: stage h via
//   L2-bypass atomic loads, 48 MFMA, gates in regs, write-through h store,
//   counter barrier (no cache-sweep fences; release = per-wave vmcnt(0)).
// Blocks [64,...): consumers. cid=(bid-64): t=cid/79, n-block=cid%79. Spin
//   until bar >= 64*(t+1), then 128x128 K=512 MFMA GEMM h_{t+1} @ fcw^T
//   with masked transposed store. Consumers keep clocks up + overlap preds
//   with the recurrence.
// LDS: producer 48*520 + 64*136 = 33,664 ush = 67,328 B -> 2 blocks/CU.
// ---------------------------------------------------------------------------
#define PBS_STR 520
#define PAS_STR 136
__global__ __launch_bounds__(256, 2) void k_fused(
    const ushort_t* __restrict__ whh_bf,   // (32,48,512)
    const ushort_t* __restrict__ gi_full,  // (31*128,1536)
    const float* __restrict__ b_hh,        // (1536)
    ushort_t* __restrict__ outs,           // (32,128,512)
    const ushort_t* __restrict__ fcw_bf,   // (10112,512)
    const float* __restrict__ fc_b,        // (10000)
    const int* __restrict__ len_i,         // (128)
    float* __restrict__ out,               // (128,31,10000)
    int* __restrict__ bar)
{
    __shared__ __align__(16) ushort_t sm[48 * PBS_STR + 64 * PAS_STR];
    const int bid = blockIdx.x;
    const int tid = threadIdx.x;
    const int w = tid >> 6, lane = tid & 63, quad = lane >> 4, lr = lane & 15;

    if (bid < NPROD_) {
        // ---------------- producer ----------------
        const int g = bid & 31;
        const int ih = bid >> 5;
        ushort_t* Bs = sm;                    // 48 x 520
        ushort_t* As = sm + 48 * PBS_STR;     // 64 x 136

        const ushort_t* wsrc = whh_bf + (size_t)g * 48 * 512;
        for (int i = tid; i < 48 * 64; i += 256) {
            const int row = i >> 6, c = i & 63;
            *(uint4*)&Bs[row * PBS_STR + c * 8] = *(const uint4*)&wsrc[row * 512 + c * 8];
        }
        const int cg = g * 16 + lr;           // gh col
        const float bhn = b_hh[1024 + cg];
        const int hold_kc = (cg >> 7) * 128;
        const int hold_off = cg & 127;
        __syncthreads();

        for (int step = 0; step < T_; ++step) {
            // gi operands (plain cached loads; gi_full is static input)
            ushort_t gi0[4], gi1[4], gi2[4];
            const size_t gbase = (size_t)step * 128 * G3_;
#pragma unroll
            for (int r = 0; r < 4; ++r) {
                const int b = ih * 64 + w * 16 + quad * 4 + r;
                const ushort_t* p = gi_full + gbase + (size_t)b * G3_ + cg;
                gi0[r] = p[0]; gi1[r] = p[512]; gi2[r] = p[1024];
            }

            f32x4 acc[3];
#pragma unroll
            for (int j = 0; j < 3; ++j) acc[j] = (f32x4){0.f, 0.f, 0.f, 0.f};
            ushort_t hraw[4];

            const ushort_t* hsrc = outs + (size_t)step * (128 * 512) + (size_t)ih * 64 * 512;
            for (int kc = 0; kc < 512; kc += 128) {
                __syncthreads();
                for (int i = tid; i < 64 * 32; i += 256) {
                    const int row = i >> 5, c8 = i & 31;
                    *(ull_t*)&As[row * PAS_STR + c8 * 4] = ald8(&hsrc[(size_t)row * 512 + kc + c8 * 4]);
                }
                __syncthreads();
#pragma unroll
                for (int kl = 0; kl < 4; ++kl) {
                    const short8 af = *(const short8*)&As[(w * 16 + lr) * PAS_STR + kl * 32 + quad * 8];
#pragma unroll
                    for (int j = 0; j < 3; ++j) {
                        const short8 bf = *(const short8*)&Bs[(j * 16 + lr) * PBS_STR + kc + kl * 32 + quad * 8];
                        acc[j] = mfma16(af, bf, acc[j]);
                    }
                }
                if (kc == hold_kc) {
#pragma unroll
                    for (int r = 0; r < 4; ++r)
                        hraw[r] = As[(w * 16 + quad * 4 + r) * PAS_STR + hold_off];
                }
            }

            // gates (C-layout: col=lr, row=quad*4+r)
            ushort_t* hdst = outs + (size_t)(step + 1) * (128 * 512);
#pragma unroll
            for (int r = 0; r < 4; ++r) {
                const int b = ih * 64 + w * 16 + quad * 4 + r;
                const float ir  = bf2f(gi0[r]);
                const float iz  = bf2f(gi1[r]);
                const float in_ = bf2f(gi2[r]);
                const float hr = acc[0][r];
                const float hz = acc[1][r];
                const float hn = acc[2][r] + bhn;
                const float rg = 1.f / (1.f + __expf(-(ir + hr)));
                const float zg = 1.f / (1.f + __expf(-(iz + hz)));
                const float nn = tanhf(in_ + rg * hn);
                const float hold = bf2f(hraw[r]);
                const float hnew = (1.f - zg) * nn + zg * hold;
                const unsigned int hv = (unsigned int)f2bf(hnew);
                const unsigned int pv = (unsigned int)__shfl_xor((int)hv, 1);
                if ((lr & 1) == 0) {
                    const unsigned int word = hv | (pv << 16);
                    __hip_atomic_store((unsigned int*)&hdst[(size_t)b * 512 + cg], word,
                                       __ATOMIC_RELAXED, __HIP_MEMORY_SCOPE_AGENT);
                }
            }

            // release: drain write-through stores, then signal
            asm volatile("s_waitcnt vmcnt(0)" ::: "memory");
            __syncthreads();
            if (tid == 0) {
                __hip_atomic_fetch_add(bar, 1, __ATOMIC_RELAXED, __HIP_MEMORY_SCOPE_AGENT);
                if (step < T_ - 1) {
                    const int target = NPROD_ * (step + 1);
                    while (__hip_atomic_load(bar, __ATOMIC_RELAXED, __HIP_MEMORY_SCOPE_AGENT) < target)
                        __builtin_amdgcn_s_sleep(1);
                }
            }
            __syncthreads();
            asm volatile("" ::: "memory");
        }
    } else {
        // ---------------- consumer (preds tile) ----------------
        const int cid = bid - NPROD_;
        const int t = cid / 79;
        const int nb = cid - t * 79;
        const int n0 = nb * 128;

        if (tid == 0) {
            const int target = NPROD_ * (t + 1);
            while (__hip_atomic_load(bar, __ATOMIC_RELAXED, __HIP_MEMORY_SCOPE_AGENT) < target)
                __builtin_amdgcn_s_sleep(32);
        }
        __syncthreads();

        ushort_t* As = sm;            // 128 x 32
        ushort_t* Bs = sm + 4096;     // 128 x 32
        const int srow = tid >> 2, ch = tid & 3;
        const int wm = (w & 1) * 64, wn = (w >> 1) * 64;
        const ushort_t* A = outs + (size_t)(t + 1) * (128 * 512);

        f32x4 acc[4][4];
        const f32x4 z4 = {0.f, 0.f, 0.f, 0.f};
#pragma unroll
        for (int i = 0; i < 4; ++i)
#pragma unroll
            for (int j = 0; j < 4; ++j) acc[i][j] = z4;

        for (int k0 = 0; k0 < 512; k0 += 32) {
            // A rows via L2-bypass 8B atomic loads (written write-through by producers)
            const ull_t a00 = ald8(&A[(size_t)srow * 512 + k0 + ch * 8]);
            const ull_t a01 = ald8(&A[(size_t)srow * 512 + k0 + ch * 8 + 4]);
            const ull_t a10 = ald8(&A[(size_t)(srow + 64) * 512 + k0 + ch * 8]);
            const ull_t a11 = ald8(&A[(size_t)(srow + 64) * 512 + k0 + ch * 8 + 4]);
            const uint4 b0 = *(const uint4*)&fcw_bf[(size_t)(n0 + srow)      * 512 + k0 + ch * 8];
            const uint4 b1 = *(const uint4*)&fcw_bf[(size_t)(n0 + srow + 64) * 512 + k0 + ch * 8];
            __syncthreads();
            *(ull_t*)&As[(srow)      * 32 + ch * 8]     = a00;
            *(ull_t*)&As[(srow)      * 32 + ch * 8 + 4] = a01;
            *(ull_t*)&As[(srow + 64) * 32 + ch * 8]     = a10;
            *(ull_t*)&As[(srow + 64) * 32 + ch * 8 + 4] = a11;
            *(uint4*)&Bs[(srow)      * 32 + ch * 8] = b0;
            *(uint4*)&Bs[(srow + 64) * 32 + ch * 8] = b1;
            __syncthreads();
            short8 af[4], bfr[4];
#pragma unroll
            for (int i = 0; i < 4; ++i) af[i]  = *(const short8*)&As[(wm + i * 16 + lr) * 32 + quad * 8];
#pragma unroll
            for (int j = 0; j < 4; ++j) bfr[j] = *(const short8*)&Bs[(wn + j * 16 + lr) * 32 + quad * 8];
#pragma unroll
            for (int i = 0; i < 4; ++i)
#pragma unroll
                for (int j = 0; j < 4; ++j) acc[i][j] = mfma16(af[i], bfr[j], acc[i][j]);
        }

#pragma unroll
        for (int i = 0; i < 4; ++i)
#pragma unroll
            for (int r = 0; r < 4; ++r) {
                const int b = wm + i * 16 + quad * 4 + r;
                const bool act = (t < len_i[b]);
                const size_t base = (size_t)b * T_ * V_ + (size_t)t * V_;
#pragma unroll
                for (int j = 0; j < 4; ++j) {
                    const int n = n0 + wn + j * 16 + lr;
                    if (n < V_) out[base + n] = act ? (acc[i][j][r] + fc_b[n]) : 0.f;
                }
            }
    }
}

// ---------------------------------------------------------------------------
extern "C" void kernel_launch(void* const* d_in, const int* in_sizes, int n_in,
                              void* d_out, int out_size, void* d_ws, size_t ws_size,
                              hipStream_t stream) {
    const float* image_code = (const float*)d_in[0];
    const int*   captions   = (const int*)d_in[1];
    const int*   cap_lens   = (const int*)d_in[2];
    const float* embed_w    = (const float*)d_in[3];
    const float* W_ih       = (const float*)d_in[4];
    const float* W_hh       = (const float*)d_in[5];
    const float* b_ih       = (const float*)d_in[6];
    const float* b_hh       = (const float*)d_in[7];
    const float* fc_w       = (const float*)d_in[8];
    const float* fc_b       = (const float*)d_in[9];
    const float* init_w     = (const float*)d_in[10];
    const float* init_b     = (const float*)d_in[11];

    float* out = (float*)d_out;
    char* ws = (char*)d_ws;
    int*      order   = (int*)(ws + WS_ORDER);
    int*      len_i   = (int*)(ws + WS_LEN);
    int*      tok     = (int*)(ws + WS_TOK);
    int*      bar     = (int*)(ws + WS_BAR);
    float*    gi_img  = (float*)(ws + WS_GIIMG);
    ushort_t* whh_bf  = (ushort_t*)(ws + WS_WHH);
    ushort_t* gi_full = (ushort_t*)(ws + WS_GIFULL);
    ushort_t* outs_bf = (ushort_t*)(ws + WS_OUTS);
    ushort_t* fcw_bf  = (ushort_t*)(ws + WS_FCW);

    // 1) sort + token table + barrier reset + int-ish outputs
    hipLaunchKernelGGL(k_prep, dim3(1), dim3(128), 0, stream,
                       captions, cap_lens, order, len_i, tok, bar,
                       out + (size_t)B_ * T_ * V_);

    // 2) weight conversions
    hipLaunchKernelGGL(k_cvt_fcw, dim3((NPAD_ * 64) / 256), dim3(256), 0, stream,
                       fc_w, fcw_bf);
    hipLaunchKernelGGL(k_cvt_whh, dim3((G3_ * H_ / 8) / 256), dim3(256), 0, stream,
                       W_hh, whh_bf);

    // 3) gi_img = ic_s @ W_ih[:, :2048]^T + b_ih
    hipLaunchKernelGGL((gemm128<true, true, EpiBiasF32>), dim3(12, 1), dim3(256), 0, stream,
                       image_code, IC_, order, W_ih, D_, IC_,
                       EpiBiasF32{gi_img, G3_, b_ih});

    // 4) h0 = ic_s @ init_w^T + init_b -> outs rows [0,128)
    hipLaunchKernelGGL((gemm128<true, true, EpiBiasBF16>), dim3(4, 1), dim3(256), 0, stream,
                       image_code, IC_, order, init_w, IC_, IC_,
                       EpiBiasBF16{outs_bf, H_, init_b});

    // 5) gi_full = emb @ W_ih[:, 2048:]^T + gi_img[b] + b_hh(r,z)
    hipLaunchKernelGGL((gemm128<true, true, EpiAdd2D>), dim3(12, 31), dim3(256), 0, stream,
                       embed_w, WD_, tok, W_ih + IC_, D_, WD_,
                       EpiAdd2D{gi_full, G3_, gi_img, G3_, b_hh});

    // 6) fused persistent recurrence + streaming output projection
    hipLaunchKernelGGL(k_fused, dim3(NPROD_ + NCONS_), dim3(256), 0, stream,
                       whh_bf, gi_full, b_hh, outs_bf,
                       fcw_bf, fc_b, len_i, out, bar);
}